// Round 15
// baseline (189.511 us; speedup 1.0000x reference)
//
#include <hip/hip_runtime.h>

#define NN 8192
#define FIN 512
#define FOUT 256
#define JS 8
#define STRIP 1024
#define NSTEP 32

typedef _Float16 f16;
typedef __attribute__((ext_vector_type(8))) _Float16 f16x8;
typedef __attribute__((ext_vector_type(4))) _Float16 f16x4;
typedef __attribute__((ext_vector_type(4))) float f32x4;
typedef __attribute__((ext_vector_type(16))) float f32x16;
typedef __attribute__((ext_vector_type(4))) int i32x4;
typedef unsigned long long u64;

__device__ __forceinline__ float lrelu(float x) { return fmaxf(x, 0.2f * x); }

// ---- convert + prep_w, heterogeneous, occupancy-UNcoupled (R14 verbatim).
__global__ void k_cvtprep(const int* __restrict__ adj, u64* __restrict__ maskG,
                          const float* __restrict__ W, f16* __restrict__ wth,
                          f16* __restrict__ wtl) {
  int bid = blockIdx.x;
  int tid = threadIdx.x;
  if (bid < NN / 4) {
    int gw = bid * 4 + (tid >> 6);
    int l = tid & 63;
    const int* src = adj + (size_t)gw * NN + 4 * l;
    u64* dst = maskG + (size_t)gw * 128;
    i32x4 v[4];
#pragma unroll
    for (int p = 0; p < 4; ++p)
      v[p] = __builtin_nontemporal_load((const i32x4*)(src + p * 256));
#pragma unroll 1
    for (int p = 0; p < 32; ++p) {
      i32x4 cur = v[p & 3];
      u64 b0 = __ballot(cur[0] > 0);
      u64 b1 = __ballot(cur[1] > 0);
      u64 b2 = __ballot(cur[2] > 0);
      u64 b3 = __ballot(cur[3] > 0);
      if (p + 4 < 32)
        v[p & 3] = __builtin_nontemporal_load((const i32x4*)(src + (p + 4) * 256));
      if (l < 4) {
        u64 bb = (l == 0) ? b0 : (l == 1) ? b1 : (l == 2) ? b2 : b3;
        dst[p * 4 + l] = bb;
      }
    }
  } else {
    int id = (bid - NN / 4) * 256 + tid;
    int c = id >> 9, k = id & 511;
    float v = W[k * FOUT + c];
    f16 a = (f16)v;
    wth[c * FIN + k] = a;
    wtl[c * FIN + k] = (f16)(v - (float)a);
  }
}

// ---- GEMM1 (R9 verbatim)
__launch_bounds__(256, 2)
__global__ void k_gemm1(const float* __restrict__ h, const f16* __restrict__ wth,
                        const f16* __restrict__ wtl, const float* __restrict__ avec,
                        f16* __restrict__ whT16, float* __restrict__ wh1,
                        float* __restrict__ wh2) {
  int i0 = blockIdx.x * 32;
  int tid = threadIdx.x;
  int w = tid >> 6, l = tid & 63, m = l & 15, g = l >> 4;
  f32x4 acc[2][4] = {};
#pragma unroll 1
  for (int k0 = 0; k0 < FIN; k0 += 32) {
    f16x8 ah[2], al[2], bh[4], bl[4];
#pragma unroll
    for (int rf = 0; rf < 2; ++rf) {
      int ro = (i0 + 16 * rf + m) * FIN + k0 + 8 * g;
      f32x4 va = *(const f32x4*)(h + ro);
      f32x4 vb = *(const f32x4*)(h + ro + 4);
#pragma unroll
      for (int e = 0; e < 4; ++e) {
        f16 x = (f16)va[e];
        ah[rf][e] = x;
        al[rf][e] = (f16)(va[e] - (float)x);
        f16 y = (f16)vb[e];
        ah[rf][4 + e] = y;
        al[rf][4 + e] = (f16)(vb[e] - (float)y);
      }
    }
#pragma unroll
    for (int cf = 0; cf < 4; ++cf) {
      int co = (64 * w + 16 * cf + m) * FIN + k0 + 8 * g;
      bh[cf] = *(const f16x8*)(wth + co);
      bl[cf] = *(const f16x8*)(wtl + co);
    }
#pragma unroll
    for (int rf = 0; rf < 2; ++rf)
#pragma unroll
      for (int cf = 0; cf < 4; ++cf) {
        acc[rf][cf] = __builtin_amdgcn_mfma_f32_16x16x32_f16(ah[rf], bh[cf], acc[rf][cf], 0, 0, 0);
        acc[rf][cf] = __builtin_amdgcn_mfma_f32_16x16x32_f16(ah[rf], bl[cf], acc[rf][cf], 0, 0, 0);
        acc[rf][cf] = __builtin_amdgcn_mfma_f32_16x16x32_f16(al[rf], bh[cf], acc[rf][cf], 0, 0, 0);
      }
  }
  __shared__ float tile[32][FOUT + 1];
#pragma unroll
  for (int rf = 0; rf < 2; ++rf)
#pragma unroll
    for (int cf = 0; cf < 4; ++cf)
#pragma unroll
      for (int r = 0; r < 4; ++r)
        tile[16 * rf + 4 * g + r][64 * w + 16 * cf + m] = acc[rf][cf][r];
  __syncthreads();
  {
    int c = tid;
    f16x8 vv[4];
#pragma unroll
    for (int r = 0; r < 32; ++r) vv[r >> 3][r & 7] = (f16)tile[r][c];
    size_t base = ((size_t)(i0 >> 4) * 256 + c) * 16;
    *(f16x8*)(whT16 + base) = vv[0];
    *(f16x8*)(whT16 + base + 8) = vv[1];
    *(f16x8*)(whT16 + base + 4096) = vv[2];
    *(f16x8*)(whT16 + base + 4096 + 8) = vv[3];
  }
  {
    int r = tid >> 3, ls = tid & 7;
    float s1 = 0.f, s2 = 0.f;
    for (int c = ls; c < FOUT; c += 8) {
      float v = tile[r][c];
      s1 = fmaf(v, avec[c], s1);
      s2 = fmaf(v, avec[FOUT + c], s2);
    }
#pragma unroll
    for (int off = 1; off < 8; off <<= 1) {
      s1 += __shfl_xor(s1, off);
      s2 += __shfl_xor(s2, off);
    }
    if (ls == 0) {
      wh1[i0 + r] = s1;
      wh2[i0 + r] = s2;
    }
  }
}

// ---- merged: global max of Wh2 + per-row/per-col exp factor tables.
__global__ void k_maxprep(const float* __restrict__ wh1, const float* __restrict__ wh2,
                          float* __restrict__ e1p, float* __restrict__ e1n,
                          float* __restrict__ thr, float* __restrict__ e2p,
                          float* __restrict__ e2n) {
  int t = threadIdx.x;
  float mx = -1e30f;
  for (int i = t; i < NN; i += 256) mx = fmaxf(mx, wh2[i]);
#pragma unroll
  for (int off = 1; off < 64; off <<= 1) mx = fmaxf(mx, __shfl_xor(mx, off));
  __shared__ float sm[4];
  if ((t & 63) == 0) sm[t >> 6] = mx;
  __syncthreads();
  float M2 = fmaxf(fmaxf(sm[0], sm[1]), fmaxf(sm[2], sm[3]));
  const float L = 1.4426950408889634f;
  int i = blockIdx.x * 256 + t;
  float w1 = wh1[i], w2 = wh2[i];
  float m = lrelu(w1 + M2);
  e1p[i] = exp2f((w1 - m) * L);
  e1n[i] = exp2f((0.2f * w1 - m) * L);
  thr[i] = exp2f(-w1 * L);
  e2p[i] = exp2f(w2 * L);
  e2n[i] = exp2f(0.2f * w2 * L);
}

// ---- fused masked-softmax + PV, 3-waves/SIMD variant. Same schedule as
// R9 (mask LDS + B LDS-dbuf + 1 barrier/step + exp-free genP), but PV uses
// mfma 16x16x32: wave = 16 rows x 256 cols -> acc = 16 x f32x4 = 64 regs
// (half of R9's 128). Lane: m=l&15 owns P-row m (computed ONCE); g=l>>4
// covers k=8g+e. Target ~154 regs -> 3 waves/SIMD. Grid 128rb x 8js.
__launch_bounds__(256, 3)
__global__ void k_attn(const u64* __restrict__ maskG, const f16* __restrict__ whT16,
                       const float* __restrict__ e1pA, const float* __restrict__ e1nA,
                       const float* __restrict__ thrA, const float* __restrict__ e2pA,
                       const float* __restrict__ e2nA, f16* __restrict__ accP,
                       float* __restrict__ zP) {
  int bx = blockIdx.x;
  int js = bx & (JS - 1), rb = bx >> 3;
  int i0b = rb * 64;
  int jbase = js * STRIP;
  int tid = threadIdx.x, w = tid >> 6, l = tid & 63;
  int m = l & 15, g = l >> 4;
  int row = i0b + w * 16 + m;

  __shared__ u64 mrow[4][16][18];
  __shared__ __align__(16) char ldsB[2][16384];

  // stage this wave's 16 rows x 16 mask words (wave-private, in-order DS)
  {
    int r = l >> 2, wd = (l & 3) * 4;
    const i32x4* src =
        (const i32x4*)(maskG + (size_t)(i0b + w * 16 + r) * 128 + js * 16 + wd);
    *(i32x4*)(&mrow[w][r][wd]) = src[0];
    *(i32x4*)(&mrow[w][r][wd + 2]) = src[1];
  }

  float E1p = e1pA[row], E1n = e1nA[row], T = thrA[row];
  f32x4 acc[16] = {};
  float za = 0.f;

  const size_t jb16 = (size_t)(jbase >> 4) * 4096;  // f16 offset of strip
  const float* e2pb = e2pA + jbase + 8 * g;
  const float* e2nb = e2nA + jbase + 8 * g;

  // B staging map (R9 verbatim): granule gg (16B) -> subtile kb=gg>>9,
  // src f16 off 8*(gg&511), lds byte = kb*8192 + (16*(gg&511))^swz
  int ldst[4];
  size_t gsrc[4];
#pragma unroll
  for (int r = 0; r < 4; ++r) {
    int gg = r * 256 + tid;
    gsrc[r] = (size_t)(gg >> 9) * 4096 + 8 * (gg & 511);
    ldst[r] = (gg >> 9) * 8192 + ((16 * (gg & 511)) ^ (((gg >> 3) & 7) << 4));
  }
  // read: lane needs B[k=8g+e][col=16cf+m]: kb=g>>1, granule n=(16cf+m)*2+(g&1)
  int kbb = (g >> 1) * 8192;
  int n0 = 2 * m + (g & 1);

  i32x4 stg[4];
#pragma unroll
  for (int r = 0; r < 4; ++r)
    stg[r] = __builtin_nontemporal_load((const i32x4*)(whT16 + jb16 + gsrc[r]));
#pragma unroll
  for (int r = 0; r < 4; ++r) *(i32x4*)(&ldsB[0][ldst[r]]) = stg[r];
  __syncthreads();

#pragma unroll 1
  for (int ch = 0; ch < 4; ++ch) {
    u64 wr0[4];
#pragma unroll
    for (int q = 0; q < 4; ++q) wr0[q] = mrow[w][m][ch * 4 + q];
#pragma unroll 1
    for (int ts = 0; ts < 8; ++ts) {
      int t = ch * 8 + ts;
      int cur = t & 1;
      int jc = t * 32;
      // issue B(t+1) global loads (latency hides under genP + MFMA)
      if (t + 1 < NSTEP) {
        const f16* src = whT16 + jb16 + (size_t)(2 * (t + 1)) * 4096;
#pragma unroll
        for (int r = 0; r < 4; ++r)
          stg[r] = __builtin_nontemporal_load((const i32x4*)(src + gsrc[r]));
      }
      // genP: 8 P/lane (row m, j = jc + 8g + 4q + e)
      int sb = ts * 8 + 2 * g;
      unsigned b4[4];
#pragma unroll
      for (int e = 0; e < 4; ++e) b4[e] = (unsigned)(wr0[e] >> sb);
      f32x4 ep0 = *(const f32x4*)(e2pb + jc);
      f32x4 en0 = *(const f32x4*)(e2nb + jc);
      f32x4 ep1 = *(const f32x4*)(e2pb + jc + 4);
      f32x4 en1 = *(const f32x4*)(e2nb + jc + 4);
      f16x8 pa;
#pragma unroll
      for (int e = 0; e < 4; ++e) {
        bool s0 = ep0[e] >= T;
        float v0 = (s0 ? E1p : E1n) * (s0 ? ep0[e] : en0[e]);
        v0 = (b4[e] & 1u) ? v0 : 0.f;
        za += v0;
        pa[e] = (f16)v0;
        bool s1 = ep1[e] >= T;
        float v1 = (s1 ? E1p : E1n) * (s1 ? ep1[e] : en1[e]);
        v1 = ((b4[e] >> 1) & 1u) ? v1 : 0.f;
        za += v1;
        pa[4 + e] = (f16)v1;
      }
      // MFMA: 16 x 16x16x32 (4 groups of 4 to cap live bf regs)
#pragma unroll
      for (int cg = 0; cg < 4; ++cg) {
        f16x8 bf[4];
#pragma unroll
        for (int c = 0; c < 4; ++c) {
          int n = n0 + 32 * (4 * cg + c);
          bf[c] = *(const f16x8*)(&ldsB[cur][kbb + ((16 * n) ^ (((n >> 3) & 7) << 4))]);
        }
#pragma unroll
        for (int c = 0; c < 4; ++c)
          acc[4 * cg + c] =
              __builtin_amdgcn_mfma_f32_16x16x32_f16(pa, bf[c], acc[4 * cg + c], 0, 0, 0);
      }
      // write B(t+1) into the other buffer, one barrier per step
      if (t + 1 < NSTEP) {
#pragma unroll
        for (int r = 0; r < 4; ++r) *(i32x4*)(&ldsB[cur ^ 1][ldst[r]]) = stg[r];
        __syncthreads();
      }
    }
  }

  // Z: 4 lanes (g) per row hold disjoint j-slots
  za += __shfl_xor(za, 16);
  za += __shfl_xor(za, 32);
  if (l < 16) zP[(size_t)js * NN + i0b + w * 16 + m] = za;

  // accP out, f16 NT. C/D 16x16: col = lane&15, row = 4*(lane>>4) + reg
  f16* ap = accP + (size_t)js * NN * FOUT;
#pragma unroll
  for (int cf = 0; cf < 16; ++cf)
#pragma unroll
    for (int r = 0; r < 4; ++r) {
      int grow = i0b + w * 16 + 4 * g + r;
      int gcol = cf * 16 + m;
      __builtin_nontemporal_store((f16)acc[cf][r], ap + (size_t)grow * FOUT + gcol);
    }
}

// ---- combine JS f16 partials, divide by Z, elu (R14 verbatim)
__global__ void k_combine(const f16* __restrict__ accP, const float* __restrict__ zP,
                          float* __restrict__ out) {
  int id = blockIdx.x * 256 + threadIdx.x;
  size_t idx = (size_t)id * 8;
  int row = (int)(idx >> 8);
  float s[8] = {};
#pragma unroll
  for (int p = 0; p < JS; ++p) {
    f16x8 v = *(const f16x8*)(accP + (size_t)p * NN * FOUT + idx);
#pragma unroll
    for (int i = 0; i < 8; ++i) s[i] += (float)v[i];
  }
  float z = 0.f;
#pragma unroll
  for (int p = 0; p < JS; ++p) z += zP[(size_t)p * NN + row];
  float inv = (z > 0.f) ? 1.f / z : 0.f;
  f32x4 o0, o1;
#pragma unroll
  for (int i = 0; i < 4; ++i) {
    float x0 = s[i] * inv;
    o0[i] = (x0 > 0.f) ? x0 : expm1f(x0);
    float x1 = s[4 + i] * inv;
    o1[i] = (x1 > 0.f) ? x1 : expm1f(x1);
  }
  *(f32x4*)(out + idx) = o0;
  *(f32x4*)(out + idx + 4) = o1;
}

extern "C" void kernel_launch(void* const* d_in, const int* in_sizes, int n_in,
                              void* d_out, int out_size, void* d_ws, size_t ws_size,
                              hipStream_t stream) {
  const float* h = (const float*)d_in[0];
  const int* adj = (const int*)d_in[1];
  const float* W = (const float*)d_in[2];
  const float* a = (const float*)d_in[3];
  (void)in_sizes; (void)n_in; (void)out_size; (void)ws_size;

  char* ws = (char*)d_ws;
  size_t off = 0;
  auto alloc = [&](size_t bytes) {
    void* p = ws + off;
    off = (off + bytes + 255) & ~(size_t)255;
    return p;
  };
  f16* accP = (f16*)alloc((size_t)JS * NN * FOUT * 2);  // 32 MB
  u64* maskG = (u64*)alloc((size_t)NN * 128 * 8);       // 8 MB
  f16* whT16 = (f16*)alloc((size_t)FOUT * NN * 2);      // 4 MB
  f16* wth = (f16*)alloc((size_t)FOUT * FIN * 2);
  f16* wtl = (f16*)alloc((size_t)FOUT * FIN * 2);
  float* wh1 = (float*)alloc((size_t)NN * 4);
  float* wh2 = (float*)alloc((size_t)NN * 4);
  float* e1p = (float*)alloc((size_t)NN * 4);
  float* e1n = (float*)alloc((size_t)NN * 4);
  float* thr = (float*)alloc((size_t)NN * 4);
  float* e2p = (float*)alloc((size_t)NN * 4);
  float* e2n = (float*)alloc((size_t)NN * 4);
  float* zP = (float*)alloc((size_t)JS * NN * 4);

  k_cvtprep<<<NN / 4 + FIN * FOUT / 256, 256, 0, stream>>>(adj, maskG, W, wth, wtl);
  k_gemm1<<<NN / 32, 256, 0, stream>>>(h, wth, wtl, a, whT16, wh1, wh2);
  k_maxprep<<<NN / 256, 256, 0, stream>>>(wh1, wh2, e1p, e1n, thr, e2p, e2n);
  k_attn<<<(NN / 64) * JS, 256, 0, stream>>>(maskG, whT16, e1p, e1n, thr, e2p, e2n,
                                             accP, zP);
  k_combine<<<NN * FOUT / 2048, 256, 0, stream>>>(accP, zP, (float*)d_out);
}

// Round 16
// 148.989 us; speedup vs baseline: 1.2720x; 1.2720x over previous
//
#include <hip/hip_runtime.h>

#define NN 8192
#define FIN 512
#define FOUT 256
#define JS 8
#define STRIP 1024
#define NSTEP 32

typedef _Float16 f16;
typedef __attribute__((ext_vector_type(8))) _Float16 f16x8;
typedef __attribute__((ext_vector_type(4))) _Float16 f16x4;
typedef __attribute__((ext_vector_type(4))) float f32x4;
typedef __attribute__((ext_vector_type(16))) float f32x16;
typedef __attribute__((ext_vector_type(4))) int i32x4;
typedef unsigned long long u64;

__device__ __forceinline__ float lrelu(float x) { return fmaxf(x, 0.2f * x); }

// ---- convert + prep_w, heterogeneous, occupancy-UNcoupled (R14 verbatim).
__global__ void k_cvtprep(const int* __restrict__ adj, u64* __restrict__ maskG,
                          const float* __restrict__ W, f16* __restrict__ wth,
                          f16* __restrict__ wtl) {
  int bid = blockIdx.x;
  int tid = threadIdx.x;
  if (bid < NN / 4) {
    int gw = bid * 4 + (tid >> 6);
    int l = tid & 63;
    const int* src = adj + (size_t)gw * NN + 4 * l;
    u64* dst = maskG + (size_t)gw * 128;
    i32x4 v[4];
#pragma unroll
    for (int p = 0; p < 4; ++p)
      v[p] = __builtin_nontemporal_load((const i32x4*)(src + p * 256));
#pragma unroll 1
    for (int p = 0; p < 32; ++p) {
      i32x4 cur = v[p & 3];
      u64 b0 = __ballot(cur[0] > 0);
      u64 b1 = __ballot(cur[1] > 0);
      u64 b2 = __ballot(cur[2] > 0);
      u64 b3 = __ballot(cur[3] > 0);
      if (p + 4 < 32)
        v[p & 3] = __builtin_nontemporal_load((const i32x4*)(src + (p + 4) * 256));
      if (l < 4) {
        u64 bb = (l == 0) ? b0 : (l == 1) ? b1 : (l == 2) ? b2 : b3;
        dst[p * 4 + l] = bb;
      }
    }
  } else {
    int id = (bid - NN / 4) * 256 + tid;
    int c = id >> 9, k = id & 511;
    float v = W[k * FOUT + c];
    f16 a = (f16)v;
    wth[c * FIN + k] = a;
    wtl[c * FIN + k] = (f16)(v - (float)a);
  }
}

// ---- GEMM1 (R9 verbatim)
__launch_bounds__(256, 2)
__global__ void k_gemm1(const float* __restrict__ h, const f16* __restrict__ wth,
                        const f16* __restrict__ wtl, const float* __restrict__ avec,
                        f16* __restrict__ whT16, float* __restrict__ wh1,
                        float* __restrict__ wh2) {
  int i0 = blockIdx.x * 32;
  int tid = threadIdx.x;
  int w = tid >> 6, l = tid & 63, m = l & 15, g = l >> 4;
  f32x4 acc[2][4] = {};
#pragma unroll 1
  for (int k0 = 0; k0 < FIN; k0 += 32) {
    f16x8 ah[2], al[2], bh[4], bl[4];
#pragma unroll
    for (int rf = 0; rf < 2; ++rf) {
      int ro = (i0 + 16 * rf + m) * FIN + k0 + 8 * g;
      f32x4 va = *(const f32x4*)(h + ro);
      f32x4 vb = *(const f32x4*)(h + ro + 4);
#pragma unroll
      for (int e = 0; e < 4; ++e) {
        f16 x = (f16)va[e];
        ah[rf][e] = x;
        al[rf][e] = (f16)(va[e] - (float)x);
        f16 y = (f16)vb[e];
        ah[rf][4 + e] = y;
        al[rf][4 + e] = (f16)(vb[e] - (float)y);
      }
    }
#pragma unroll
    for (int cf = 0; cf < 4; ++cf) {
      int co = (64 * w + 16 * cf + m) * FIN + k0 + 8 * g;
      bh[cf] = *(const f16x8*)(wth + co);
      bl[cf] = *(const f16x8*)(wtl + co);
    }
#pragma unroll
    for (int rf = 0; rf < 2; ++rf)
#pragma unroll
      for (int cf = 0; cf < 4; ++cf) {
        acc[rf][cf] = __builtin_amdgcn_mfma_f32_16x16x32_f16(ah[rf], bh[cf], acc[rf][cf], 0, 0, 0);
        acc[rf][cf] = __builtin_amdgcn_mfma_f32_16x16x32_f16(ah[rf], bl[cf], acc[rf][cf], 0, 0, 0);
        acc[rf][cf] = __builtin_amdgcn_mfma_f32_16x16x32_f16(al[rf], bh[cf], acc[rf][cf], 0, 0, 0);
      }
  }
  __shared__ float tile[32][FOUT + 1];
#pragma unroll
  for (int rf = 0; rf < 2; ++rf)
#pragma unroll
    for (int cf = 0; cf < 4; ++cf)
#pragma unroll
      for (int r = 0; r < 4; ++r)
        tile[16 * rf + 4 * g + r][64 * w + 16 * cf + m] = acc[rf][cf][r];
  __syncthreads();
  {
    int c = tid;
    f16x8 vv[4];
#pragma unroll
    for (int r = 0; r < 32; ++r) vv[r >> 3][r & 7] = (f16)tile[r][c];
    size_t base = ((size_t)(i0 >> 4) * 256 + c) * 16;
    *(f16x8*)(whT16 + base) = vv[0];
    *(f16x8*)(whT16 + base + 8) = vv[1];
    *(f16x8*)(whT16 + base + 4096) = vv[2];
    *(f16x8*)(whT16 + base + 4096 + 8) = vv[3];
  }
  {
    int r = tid >> 3, ls = tid & 7;
    float s1 = 0.f, s2 = 0.f;
    for (int c = ls; c < FOUT; c += 8) {
      float v = tile[r][c];
      s1 = fmaf(v, avec[c], s1);
      s2 = fmaf(v, avec[FOUT + c], s2);
    }
#pragma unroll
    for (int off = 1; off < 8; off <<= 1) {
      s1 += __shfl_xor(s1, off);
      s2 += __shfl_xor(s2, off);
    }
    if (ls == 0) {
      wh1[i0 + r] = s1;
      wh2[i0 + r] = s2;
    }
  }
}

// ---- fused masked-softmax + PV (R14 schedule, tables computed in-block).
// Prologue additionally computes M2 = max(wh2) (deterministic, identical in
// every block), the per-row factors E1p/E1n/T, and the strip's e2p/e2n
// tables into LDS — replacing the separate k_maxprep kernel and its global
// table round-trip. Wave = 32 rows x 256 cols x 1024-j strip; masks
// wave-private in LDS; B staged via LDS dbuf (reg-split, XOR swizzle), one
// barrier/step; exp-free genP. acc[8] f32x16 = 128 AGPR. Grid 64rb x 8js.
__launch_bounds__(256, 2)
__global__ void k_attn(const u64* __restrict__ maskG, const f16* __restrict__ whT16,
                       const float* __restrict__ wh1, const float* __restrict__ wh2,
                       f16* __restrict__ accP, float* __restrict__ zP) {
  int bx = blockIdx.x;
  int js = bx & (JS - 1), rb = bx >> 3;
  int i0b = rb * 128;
  int jbase = js * STRIP;
  int tid = threadIdx.x, w = tid >> 6, l = tid & 63;
  int lr = l & 31, hi = l >> 5;
  int row = i0b + w * 32 + lr;

  __shared__ u64 mrow[4][32][18];
  __shared__ __align__(16) char ldsB[2][16384];
  __shared__ __align__(16) float e2pL[STRIP];
  __shared__ __align__(16) float e2nL[STRIP];
  __shared__ float sm[4];

  // stage this wave's 32 rows x 16 mask words (wave-private, in-order DS)
#pragma unroll
  for (int p = 0; p < 4; ++p) {
    int r = 8 * p + (l >> 3);
    const i32x4* src =
        (const i32x4*)(maskG + (size_t)(i0b + 32 * w + r) * 128 + js * 16) + (l & 7);
    *(i32x4*)(&mrow[w][r][(l & 7) * 2]) = *src;
  }

  // M2 = global max of wh2 (32 KB L2 scan, same deterministic result in
  // every block)
  float mx = -1e30f;
  for (int i = tid; i < NN; i += 256) mx = fmaxf(mx, wh2[i]);
#pragma unroll
  for (int off = 1; off < 64; off <<= 1) mx = fmaxf(mx, __shfl_xor(mx, off));
  if (l == 0) sm[w] = mx;
  __syncthreads();
  float M2 = fmaxf(fmaxf(sm[0], sm[1]), fmaxf(sm[2], sm[3]));
  const float L = 1.4426950408889634f;
  // strip e2 tables -> LDS
  for (int jj = tid; jj < STRIP; jj += 256) {
    float w2 = wh2[jbase + jj];
    e2pL[jj] = exp2f(w2 * L);
    e2nL[jj] = exp2f(0.2f * w2 * L);
  }
  // per-row factors
  float w1 = wh1[row];
  float mr = lrelu(w1 + M2);
  float E1p = exp2f((w1 - mr) * L);
  float E1n = exp2f((0.2f * w1 - mr) * L);
  float T = exp2f(-w1 * L);

  f32x16 acc[8] = {};
  float za = 0.f;

  const size_t jb16 = (size_t)(jbase >> 4) * 4096;  // f16 offset of strip

  // staging map: granule g (16B) -> tile kb=g>>9, src f16 off 8*(g&511),
  // lds byte = kb*8192 + (16*(g&511)) ^ (((g>>3)&7)<<4)   [swizzle]
  int ldst[4];
  size_t gsrc[4];
#pragma unroll
  for (int r = 0; r < 4; ++r) {
    int g = r * 256 + tid;
    gsrc[r] = (size_t)(g >> 9) * 4096 + 8 * (g & 511);
    ldst[r] = (g >> 9) * 8192 + ((16 * (g & 511)) ^ (((g >> 3) & 7) << 4));
  }
  // per-lane conflict-free read base: (row,slot) bijective per 128B row
  int rdbase = (lr * 32 + hi * 16) ^ (((lr >> 2) & 7) << 4);

  i32x4 stg[4];
  // prologue: stage B(0); barrier also publishes e2 tables
#pragma unroll
  for (int r = 0; r < 4; ++r)
    stg[r] = __builtin_nontemporal_load((const i32x4*)(whT16 + jb16 + gsrc[r]));
#pragma unroll
  for (int r = 0; r < 4; ++r) *(i32x4*)(&ldsB[0][ldst[r]]) = stg[r];
  __syncthreads();

#pragma unroll 1
  for (int ch = 0; ch < 4; ++ch) {
    u64 wr0[4];
#pragma unroll
    for (int q = 0; q < 4; ++q) wr0[q] = mrow[w][lr][ch * 4 + q];
#pragma unroll 1
    for (int ts = 0; ts < 8; ++ts) {
      int t = ch * 8 + ts;
      int cur = t & 1;
      int jc = t * 32;
      // issue B(t+1) global loads (latency hides under genP + MFMA)
      if (t + 1 < NSTEP) {
        const f16* src = whT16 + jb16 + (size_t)(2 * (t + 1)) * 4096;
#pragma unroll
        for (int r = 0; r < 4; ++r)
          stg[r] = __builtin_nontemporal_load((const i32x4*)(src + gsrc[r]));
      }
      // genP: 16 P/lane, exp-free (bit lbit of word e <-> j=..+4*lbit+e)
      int sb = ts * 8 + 2 * hi;
      unsigned b4[4];
#pragma unroll
      for (int e = 0; e < 4; ++e) b4[e] = (unsigned)(wr0[e] >> sb);
      f16x8 pa0, pa1;
#pragma unroll
      for (int q = 0; q < 2; ++q) {
        int fo = jc + 8 * hi + 4 * q;
        f32x4 ep0 = *(const f32x4*)(&e2pL[fo]);
        f32x4 en0 = *(const f32x4*)(&e2nL[fo]);
        f32x4 ep1 = *(const f32x4*)(&e2pL[fo + 16]);
        f32x4 en1 = *(const f32x4*)(&e2nL[fo + 16]);
#pragma unroll
        for (int e = 0; e < 4; ++e) {
          int f = 4 * q + e;
          bool s0 = ep0[e] >= T;
          float v0 = (s0 ? E1p : E1n) * (s0 ? ep0[e] : en0[e]);
          v0 = ((b4[e] >> q) & 1u) ? v0 : 0.f;
          za += v0;
          pa0[f] = (f16)v0;
          bool s1 = ep1[e] >= T;
          float v1 = (s1 ? E1p : E1n) * (s1 ? ep1[e] : en1[e]);
          v1 = ((b4[e] >> (4 + q)) & 1u) ? v1 : 0.f;
          za += v1;
          pa1[f] = (f16)v1;
        }
      }
      // MFMA from LDS (conflict-free swizzled reads)
#pragma unroll
      for (int cf = 0; cf < 8; ++cf) {
        f16x8 bf0 = *(const f16x8*)(&ldsB[cur][cf * 1024 + rdbase]);
        acc[cf] = __builtin_amdgcn_mfma_f32_32x32x16_f16(pa0, bf0, acc[cf], 0, 0, 0);
      }
#pragma unroll
      for (int cf = 0; cf < 8; ++cf) {
        f16x8 bf1 = *(const f16x8*)(&ldsB[cur][8192 + cf * 1024 + rdbase]);
        acc[cf] = __builtin_amdgcn_mfma_f32_32x32x16_f16(pa1, bf1, acc[cf], 0, 0, 0);
      }
      // write B(t+1) into the other buffer, one barrier per step
      if (t + 1 < NSTEP) {
#pragma unroll
        for (int r = 0; r < 4; ++r) *(i32x4*)(&ldsB[cur ^ 1][ldst[r]]) = stg[r];
        __syncthreads();
      }
    }
  }

  // Z: hi=0/1 lanes hold complementary j-slots of row
  za += __shfl_xor(za, 32);
  if (hi == 0) zP[(size_t)js * NN + row] = za;

  // partial accumulator out, f16 NT. C/D: col=lane&31, row=(r&3)+8*(r>>2)+4*hi
  f16* ap = accP + (size_t)js * NN * FOUT;
#pragma unroll
  for (int c = 0; c < 8; ++c)
#pragma unroll
    for (int r = 0; r < 16; ++r) {
      int grow = i0b + 32 * w + (r & 3) + 8 * (r >> 2) + 4 * hi;
      int gcol = c * 32 + lr;
      __builtin_nontemporal_store((f16)acc[c][r], ap + (size_t)grow * FOUT + gcol);
    }
}

// ---- combine JS f16 partials, divide by Z, elu (R14 verbatim)
__global__ void k_combine(const f16* __restrict__ accP, const float* __restrict__ zP,
                          float* __restrict__ out) {
  int id = blockIdx.x * 256 + threadIdx.x;
  size_t idx = (size_t)id * 8;
  int row = (int)(idx >> 8);
  float s[8] = {};
#pragma unroll
  for (int p = 0; p < JS; ++p) {
    f16x8 v = *(const f16x8*)(accP + (size_t)p * NN * FOUT + idx);
#pragma unroll
    for (int i = 0; i < 8; ++i) s[i] += (float)v[i];
  }
  float z = 0.f;
#pragma unroll
  for (int p = 0; p < JS; ++p) z += zP[(size_t)p * NN + row];
  float inv = (z > 0.f) ? 1.f / z : 0.f;
  f32x4 o0, o1;
#pragma unroll
  for (int i = 0; i < 4; ++i) {
    float x0 = s[i] * inv;
    o0[i] = (x0 > 0.f) ? x0 : expm1f(x0);
    float x1 = s[4 + i] * inv;
    o1[i] = (x1 > 0.f) ? x1 : expm1f(x1);
  }
  *(f32x4*)(out + idx) = o0;
  *(f32x4*)(out + idx + 4) = o1;
}

extern "C" void kernel_launch(void* const* d_in, const int* in_sizes, int n_in,
                              void* d_out, int out_size, void* d_ws, size_t ws_size,
                              hipStream_t stream) {
  const float* h = (const float*)d_in[0];
  const int* adj = (const int*)d_in[1];
  const float* W = (const float*)d_in[2];
  const float* a = (const float*)d_in[3];
  (void)in_sizes; (void)n_in; (void)out_size; (void)ws_size;

  char* ws = (char*)d_ws;
  size_t off = 0;
  auto alloc = [&](size_t bytes) {
    void* p = ws + off;
    off = (off + bytes + 255) & ~(size_t)255;
    return p;
  };
  f16* accP = (f16*)alloc((size_t)JS * NN * FOUT * 2);  // 32 MB
  u64* maskG = (u64*)alloc((size_t)NN * 128 * 8);       // 8 MB
  f16* whT16 = (f16*)alloc((size_t)FOUT * NN * 2);      // 4 MB
  f16* wth = (f16*)alloc((size_t)FOUT * FIN * 2);
  f16* wtl = (f16*)alloc((size_t)FOUT * FIN * 2);
  float* wh1 = (float*)alloc((size_t)NN * 4);
  float* wh2 = (float*)alloc((size_t)NN * 4);
  float* zP = (float*)alloc((size_t)JS * NN * 4);

  k_cvtprep<<<NN / 4 + FIN * FOUT / 256, 256, 0, stream>>>(adj, maskG, W, wth, wtl);
  k_gemm1<<<NN / 32, 256, 0, stream>>>(h, wth, wtl, a, whT16, wh1, wh2);
  k_attn<<<(NN / 128) * JS, 256, 0, stream>>>(maskG, whT16, wh1, wh2, accP, zP);
  k_combine<<<NN * FOUT / 2048, 256, 0, stream>>>(accP, zP, (float*)d_out);
}

// Round 17
// 147.258 us; speedup vs baseline: 1.2869x; 1.0118x over previous
//
#include <hip/hip_runtime.h>

#define NN 8192
#define FIN 512
#define FOUT 256
#define JS 8
#define STRIP 1024
#define NSTEP 32

typedef _Float16 f16;
typedef __attribute__((ext_vector_type(8))) _Float16 f16x8;
typedef __attribute__((ext_vector_type(4))) _Float16 f16x4;
typedef __attribute__((ext_vector_type(4))) float f32x4;
typedef __attribute__((ext_vector_type(16))) float f32x16;
typedef __attribute__((ext_vector_type(4))) int i32x4;
typedef unsigned long long u64;

__device__ __forceinline__ float lrelu(float x) { return fmaxf(x, 0.2f * x); }

// ---- convert + prep_w, heterogeneous, occupancy-UNcoupled (R14 verbatim).
__global__ void k_cvtprep(const int* __restrict__ adj, u64* __restrict__ maskG,
                          const float* __restrict__ W, f16* __restrict__ wth,
                          f16* __restrict__ wtl) {
  int bid = blockIdx.x;
  int tid = threadIdx.x;
  if (bid < NN / 4) {
    int gw = bid * 4 + (tid >> 6);
    int l = tid & 63;
    const int* src = adj + (size_t)gw * NN + 4 * l;
    u64* dst = maskG + (size_t)gw * 128;
    i32x4 v[4];
#pragma unroll
    for (int p = 0; p < 4; ++p)
      v[p] = __builtin_nontemporal_load((const i32x4*)(src + p * 256));
#pragma unroll 1
    for (int p = 0; p < 32; ++p) {
      i32x4 cur = v[p & 3];
      u64 b0 = __ballot(cur[0] > 0);
      u64 b1 = __ballot(cur[1] > 0);
      u64 b2 = __ballot(cur[2] > 0);
      u64 b3 = __ballot(cur[3] > 0);
      if (p + 4 < 32)
        v[p & 3] = __builtin_nontemporal_load((const i32x4*)(src + (p + 4) * 256));
      if (l < 4) {
        u64 bb = (l == 0) ? b0 : (l == 1) ? b1 : (l == 2) ? b2 : b3;
        dst[p * 4 + l] = bb;
      }
    }
  } else {
    int id = (bid - NN / 4) * 256 + tid;
    int c = id >> 9, k = id & 511;
    float v = W[k * FOUT + c];
    f16 a = (f16)v;
    wth[c * FIN + k] = a;
    wtl[c * FIN + k] = (f16)(v - (float)a);
  }
}

// ---- GEMM1 (R9 verbatim)
__launch_bounds__(256, 2)
__global__ void k_gemm1(const float* __restrict__ h, const f16* __restrict__ wth,
                        const f16* __restrict__ wtl, const float* __restrict__ avec,
                        f16* __restrict__ whT16, float* __restrict__ wh1,
                        float* __restrict__ wh2) {
  int i0 = blockIdx.x * 32;
  int tid = threadIdx.x;
  int w = tid >> 6, l = tid & 63, m = l & 15, g = l >> 4;
  f32x4 acc[2][4] = {};
#pragma unroll 1
  for (int k0 = 0; k0 < FIN; k0 += 32) {
    f16x8 ah[2], al[2], bh[4], bl[4];
#pragma unroll
    for (int rf = 0; rf < 2; ++rf) {
      int ro = (i0 + 16 * rf + m) * FIN + k0 + 8 * g;
      f32x4 va = *(const f32x4*)(h + ro);
      f32x4 vb = *(const f32x4*)(h + ro + 4);
#pragma unroll
      for (int e = 0; e < 4; ++e) {
        f16 x = (f16)va[e];
        ah[rf][e] = x;
        al[rf][e] = (f16)(va[e] - (float)x);
        f16 y = (f16)vb[e];
        ah[rf][4 + e] = y;
        al[rf][4 + e] = (f16)(vb[e] - (float)y);
      }
    }
#pragma unroll
    for (int cf = 0; cf < 4; ++cf) {
      int co = (64 * w + 16 * cf + m) * FIN + k0 + 8 * g;
      bh[cf] = *(const f16x8*)(wth + co);
      bl[cf] = *(const f16x8*)(wtl + co);
    }
#pragma unroll
    for (int rf = 0; rf < 2; ++rf)
#pragma unroll
      for (int cf = 0; cf < 4; ++cf) {
        acc[rf][cf] = __builtin_amdgcn_mfma_f32_16x16x32_f16(ah[rf], bh[cf], acc[rf][cf], 0, 0, 0);
        acc[rf][cf] = __builtin_amdgcn_mfma_f32_16x16x32_f16(ah[rf], bl[cf], acc[rf][cf], 0, 0, 0);
        acc[rf][cf] = __builtin_amdgcn_mfma_f32_16x16x32_f16(al[rf], bh[cf], acc[rf][cf], 0, 0, 0);
      }
  }
  __shared__ float tile[32][FOUT + 1];
#pragma unroll
  for (int rf = 0; rf < 2; ++rf)
#pragma unroll
    for (int cf = 0; cf < 4; ++cf)
#pragma unroll
      for (int r = 0; r < 4; ++r)
        tile[16 * rf + 4 * g + r][64 * w + 16 * cf + m] = acc[rf][cf][r];
  __syncthreads();
  {
    int c = tid;
    f16x8 vv[4];
#pragma unroll
    for (int r = 0; r < 32; ++r) vv[r >> 3][r & 7] = (f16)tile[r][c];
    size_t base = ((size_t)(i0 >> 4) * 256 + c) * 16;
    *(f16x8*)(whT16 + base) = vv[0];
    *(f16x8*)(whT16 + base + 8) = vv[1];
    *(f16x8*)(whT16 + base + 4096) = vv[2];
    *(f16x8*)(whT16 + base + 4096 + 8) = vv[3];
  }
  {
    int r = tid >> 3, ls = tid & 7;
    float s1 = 0.f, s2 = 0.f;
    for (int c = ls; c < FOUT; c += 8) {
      float v = tile[r][c];
      s1 = fmaf(v, avec[c], s1);
      s2 = fmaf(v, avec[FOUT + c], s2);
    }
#pragma unroll
    for (int off = 1; off < 8; off <<= 1) {
      s1 += __shfl_xor(s1, off);
      s2 += __shfl_xor(s2, off);
    }
    if (ls == 0) {
      wh1[i0 + r] = s1;
      wh2[i0 + r] = s2;
    }
  }
}

// ---- fused masked-softmax + PV (R16 schedule; genP uses the exact
// max-identity exp(lrelu(s)-m) = max(E1p*ep, E1n*en), dropping the T
// compare/select chain). accP stores are cache-resident (no NT) so
// k_combine reads from L2/L3 instead of HBM. Wave = 32 rows x 256 cols x
// 1024-j strip; masks wave-private in LDS; B staged via LDS dbuf
// (reg-split, XOR swizzle), one barrier/step. acc[8] f32x16 = 128 AGPR.
// Grid 64rb x 8js.
__launch_bounds__(256, 2)
__global__ void k_attn(const u64* __restrict__ maskG, const f16* __restrict__ whT16,
                       const float* __restrict__ wh1, const float* __restrict__ wh2,
                       f16* __restrict__ accP, float* __restrict__ zP) {
  int bx = blockIdx.x;
  int js = bx & (JS - 1), rb = bx >> 3;
  int i0b = rb * 128;
  int jbase = js * STRIP;
  int tid = threadIdx.x, w = tid >> 6, l = tid & 63;
  int lr = l & 31, hi = l >> 5;
  int row = i0b + w * 32 + lr;

  __shared__ u64 mrow[4][32][18];
  __shared__ __align__(16) char ldsB[2][16384];
  __shared__ __align__(16) float e2pL[STRIP];
  __shared__ __align__(16) float e2nL[STRIP];
  __shared__ float sm[4];

  // stage this wave's 32 rows x 16 mask words (wave-private, in-order DS)
#pragma unroll
  for (int p = 0; p < 4; ++p) {
    int r = 8 * p + (l >> 3);
    const i32x4* src =
        (const i32x4*)(maskG + (size_t)(i0b + 32 * w + r) * 128 + js * 16) + (l & 7);
    *(i32x4*)(&mrow[w][r][(l & 7) * 2]) = *src;
  }

  // M2 = global max of wh2 (deterministic, identical in every block)
  float mx = -1e30f;
  for (int i = tid; i < NN; i += 256) mx = fmaxf(mx, wh2[i]);
#pragma unroll
  for (int off = 1; off < 64; off <<= 1) mx = fmaxf(mx, __shfl_xor(mx, off));
  if (l == 0) sm[w] = mx;
  __syncthreads();
  float M2 = fmaxf(fmaxf(sm[0], sm[1]), fmaxf(sm[2], sm[3]));
  const float L = 1.4426950408889634f;
  // strip e2 tables -> LDS
  for (int jj = tid; jj < STRIP; jj += 256) {
    float w2 = wh2[jbase + jj];
    e2pL[jj] = exp2f(w2 * L);
    e2nL[jj] = exp2f(0.2f * w2 * L);
  }
  // per-row factors (max-identity: no threshold needed)
  float w1 = wh1[row];
  float mr = lrelu(w1 + M2);
  float E1p = exp2f((w1 - mr) * L);
  float E1n = exp2f((0.2f * w1 - mr) * L);

  f32x16 acc[8] = {};
  float za = 0.f;

  const size_t jb16 = (size_t)(jbase >> 4) * 4096;  // f16 offset of strip

  // staging map: granule g (16B) -> tile kb=g>>9, src f16 off 8*(g&511),
  // lds byte = kb*8192 + (16*(g&511)) ^ (((g>>3)&7)<<4)   [swizzle]
  int ldst[4];
  size_t gsrc[4];
#pragma unroll
  for (int r = 0; r < 4; ++r) {
    int g = r * 256 + tid;
    gsrc[r] = (size_t)(g >> 9) * 4096 + 8 * (g & 511);
    ldst[r] = (g >> 9) * 8192 + ((16 * (g & 511)) ^ (((g >> 3) & 7) << 4));
  }
  // per-lane conflict-free read base: (row,slot) bijective per 128B row
  int rdbase = (lr * 32 + hi * 16) ^ (((lr >> 2) & 7) << 4);

  i32x4 stg[4];
  // prologue: stage B(0); barrier also publishes e2 tables
#pragma unroll
  for (int r = 0; r < 4; ++r)
    stg[r] = __builtin_nontemporal_load((const i32x4*)(whT16 + jb16 + gsrc[r]));
#pragma unroll
  for (int r = 0; r < 4; ++r) *(i32x4*)(&ldsB[0][ldst[r]]) = stg[r];
  __syncthreads();

#pragma unroll 1
  for (int ch = 0; ch < 4; ++ch) {
    u64 wr0[4];
#pragma unroll
    for (int q = 0; q < 4; ++q) wr0[q] = mrow[w][lr][ch * 4 + q];
#pragma unroll 1
    for (int ts = 0; ts < 8; ++ts) {
      int t = ch * 8 + ts;
      int cur = t & 1;
      int jc = t * 32;
      // issue B(t+1) global loads (latency hides under genP + MFMA)
      if (t + 1 < NSTEP) {
        const f16* src = whT16 + jb16 + (size_t)(2 * (t + 1)) * 4096;
#pragma unroll
        for (int r = 0; r < 4; ++r)
          stg[r] = __builtin_nontemporal_load((const i32x4*)(src + gsrc[r]));
      }
      // genP: 16 P/lane via exact max-identity
      int sb = ts * 8 + 2 * hi;
      unsigned b4[4];
#pragma unroll
      for (int e = 0; e < 4; ++e) b4[e] = (unsigned)(wr0[e] >> sb);
      f16x8 pa0, pa1;
#pragma unroll
      for (int q = 0; q < 2; ++q) {
        int fo = jc + 8 * hi + 4 * q;
        f32x4 ep0 = *(const f32x4*)(&e2pL[fo]);
        f32x4 en0 = *(const f32x4*)(&e2nL[fo]);
        f32x4 ep1 = *(const f32x4*)(&e2pL[fo + 16]);
        f32x4 en1 = *(const f32x4*)(&e2nL[fo + 16]);
#pragma unroll
        for (int e = 0; e < 4; ++e) {
          int f = 4 * q + e;
          float v0 = fmaxf(E1p * ep0[e], E1n * en0[e]);
          v0 = ((b4[e] >> q) & 1u) ? v0 : 0.f;
          za += v0;
          pa0[f] = (f16)v0;
          float v1 = fmaxf(E1p * ep1[e], E1n * en1[e]);
          v1 = ((b4[e] >> (4 + q)) & 1u) ? v1 : 0.f;
          za += v1;
          pa1[f] = (f16)v1;
        }
      }
      // MFMA from LDS (conflict-free swizzled reads)
#pragma unroll
      for (int cf = 0; cf < 8; ++cf) {
        f16x8 bf0 = *(const f16x8*)(&ldsB[cur][cf * 1024 + rdbase]);
        acc[cf] = __builtin_amdgcn_mfma_f32_32x32x16_f16(pa0, bf0, acc[cf], 0, 0, 0);
      }
#pragma unroll
      for (int cf = 0; cf < 8; ++cf) {
        f16x8 bf1 = *(const f16x8*)(&ldsB[cur][8192 + cf * 1024 + rdbase]);
        acc[cf] = __builtin_amdgcn_mfma_f32_32x32x16_f16(pa1, bf1, acc[cf], 0, 0, 0);
      }
      // write B(t+1) into the other buffer, one barrier per step
      if (t + 1 < NSTEP) {
#pragma unroll
        for (int r = 0; r < 4; ++r) *(i32x4*)(&ldsB[cur ^ 1][ldst[r]]) = stg[r];
        __syncthreads();
      }
    }
  }

  // Z: hi=0/1 lanes hold complementary j-slots of row
  za += __shfl_xor(za, 32);
  if (hi == 0) zP[(size_t)js * NN + row] = za;

  // partial accumulator out, f16 (cache-resident: combine reads it next).
  // C/D: col=lane&31, row=(r&3)+8*(r>>2)+4*hi
  f16* ap = accP + (size_t)js * NN * FOUT;
#pragma unroll
  for (int c = 0; c < 8; ++c)
#pragma unroll
    for (int r = 0; r < 16; ++r) {
      int grow = i0b + 32 * w + (r & 3) + 8 * (r >> 2) + 4 * hi;
      int gcol = c * 32 + lr;
      ap[(size_t)grow * FOUT + gcol] = (f16)acc[c][r];
    }
}

// ---- combine JS f16 partials (L2/L3-resident), divide by Z, elu.
__global__ void k_combine(const f16* __restrict__ accP, const float* __restrict__ zP,
                          float* __restrict__ out) {
  int id = blockIdx.x * 256 + threadIdx.x;
  size_t idx = (size_t)id * 8;
  int row = (int)(idx >> 8);
  float s[8] = {};
#pragma unroll
  for (int p = 0; p < JS; ++p) {
    f16x8 v = *(const f16x8*)(accP + (size_t)p * NN * FOUT + idx);
#pragma unroll
    for (int i = 0; i < 8; ++i) s[i] += (float)v[i];
  }
  float z = 0.f;
#pragma unroll
  for (int p = 0; p < JS; ++p) z += zP[(size_t)p * NN + row];
  float inv = (z > 0.f) ? 1.f / z : 0.f;
  f32x4 o0, o1;
#pragma unroll
  for (int i = 0; i < 4; ++i) {
    float x0 = s[i] * inv;
    o0[i] = (x0 > 0.f) ? x0 : expm1f(x0);
    float x1 = s[4 + i] * inv;
    o1[i] = (x1 > 0.f) ? x1 : expm1f(x1);
  }
  *(f32x4*)(out + idx) = o0;
  *(f32x4*)(out + idx + 4) = o1;
}

extern "C" void kernel_launch(void* const* d_in, const int* in_sizes, int n_in,
                              void* d_out, int out_size, void* d_ws, size_t ws_size,
                              hipStream_t stream) {
  const float* h = (const float*)d_in[0];
  const int* adj = (const int*)d_in[1];
  const float* W = (const float*)d_in[2];
  const float* a = (const float*)d_in[3];
  (void)in_sizes; (void)n_in; (void)out_size; (void)ws_size;

  char* ws = (char*)d_ws;
  size_t off = 0;
  auto alloc = [&](size_t bytes) {
    void* p = ws + off;
    off = (off + bytes + 255) & ~(size_t)255;
    return p;
  };
  f16* accP = (f16*)alloc((size_t)JS * NN * FOUT * 2);  // 32 MB
  u64* maskG = (u64*)alloc((size_t)NN * 128 * 8);       // 8 MB
  f16* whT16 = (f16*)alloc((size_t)FOUT * NN * 2);      // 4 MB
  f16* wth = (f16*)alloc((size_t)FOUT * FIN * 2);
  f16* wtl = (f16*)alloc((size_t)FOUT * FIN * 2);
  float* wh1 = (float*)alloc((size_t)NN * 4);
  float* wh2 = (float*)alloc((size_t)NN * 4);
  float* zP = (float*)alloc((size_t)JS * NN * 4);

  k_cvtprep<<<NN / 4 + FIN * FOUT / 256, 256, 0, stream>>>(adj, maskG, W, wth, wtl);
  k_gemm1<<<NN / 32, 256, 0, stream>>>(h, wth, wtl, a, whT16, wh1, wh2);
  k_attn<<<(NN / 128) * JS, 256, 0, stream>>>(maskG, whT16, wh1, wh2, accP, zP);
  k_combine<<<NN * FOUT / 2048, 256, 0, stream>>>(accP, zP, (float*)d_out);
}